// Round 6
// baseline (3363.737 us; speedup 1.0000x reference)
//
#include <hip/hip_runtime.h>
#include <hip/hip_bf16.h>
#include <math.h>

using bf16 = __hip_bfloat16;
using short8 = __attribute__((ext_vector_type(8))) short;
using f32x4  = __attribute__((ext_vector_type(4))) float;

#define B_     128
#define T_     64
#define EMB_   1536
#define ACT_   12
#define STOCH_ 32
#define DETER_ 1024
#define HID_   1024
#define GRUN_  3072
#define GRUK_  2048
#define OBSK_  2560
#define OUTW_  1216   // 6*STOCH + DETER

// canonical f32 param block offsets (floats)
#define PW1   0
#define Pb1   45056
#define Pg1   46080
#define Pbn1  47104
#define Pbg   48128
#define Pgg   51200
#define Pbng  54272
#define Pb3   57344
#define Pg3   62464
#define Pbn3  67584
#define Pb4   72704
#define Pb5   73024
#define Pg5   74048
#define Pbn5  75072
#define Pb6   76096
#define PW4   76160
#define PW6   403840
#define PTOT  469376

__device__ inline float bf2f(bf16 v){ return __bfloat162float(v); }
__device__ inline bf16  f2bf(float v){ return __float2bfloat16(v); }
__device__ inline float elu_(float x){ return x > 0.f ? x : expm1f(x); }
__device__ inline float sigm_(float x){ return 1.f/(1.f+expf(-x)); }
__device__ inline float softplus_(float x){ return fmaxf(x,0.f) + log1pf(expf(-fabsf(x))); }
__device__ inline void stout(void* out, int dt, size_t i, float v){
  if(dt) ((bf16*)out)[i] = f2bf(v); else ((float*)out)[i] = v;
}
__device__ inline float maskv(const void* isf, int enc, int idx){
  float fv;
  if(enc==0)      fv = (float)((const int*)isf)[idx];
  else if(enc==1) fv = (float)((const unsigned char*)isf)[idx];
  else if(enc==2) fv = bf2f(((const bf16*)isf)[idx]);
  else            fv = ((const float*)isf)[idx];
  return (fv != 0.f) ? 0.f : 1.f;
}

// nw-wave block reduction of two values (sum, sumsq); sm needs 2*nw floats
__device__ inline void block_reduce2w(float& a, float& b, float* sm, int nw){
  __syncthreads();
  for(int off=32; off>0; off>>=1){
    a += __shfl_down(a, off);
    b += __shfl_down(b, off);
  }
  int w = threadIdx.x >> 6;
  if((threadIdx.x & 63) == 0){ sm[2*w] = a; sm[2*w+1] = b; }
  __syncthreads();
  float sa = 0.f, sb = 0.f;
  for(int i=0;i<nw;i++){ sa += sm[2*i]; sb += sm[2*i+1]; }
  a = sa; b = sb;
}

// ---- detect: block 0 = float dtype (dflag[0]); block 1 = is_first enc (dflag[1]) ----
__global__ void k_detect(const unsigned short* emb, const unsigned char* isf, int* dflag){
  __shared__ int c0, c1, c2;
  if(threadIdx.x==0){ c0=0; c1=0; c2=0; }
  __syncthreads();
  if(blockIdx.x == 0){
    int c = 0;
    for(int i=threadIdx.x; i<2048; i+=256){
      unsigned short u = emb[2*i];
      int exp8 = (u >> 7) & 0xFF;
      if(exp8 > 140) c++;
    }
    atomicAdd(&c0, c);
    __syncthreads();
    if(threadIdx.x==0) dflag[0] = (c0 < 100) ? 1 : 0;
  } else {
    for(int i=threadIdx.x; i<B_*T_; i+=256){
      unsigned char c = isf[i];
      if(c == 0x3F){
        if((i & 3) == 1) atomicOr(&c0, 1);
        else if((i & 3) == 3) atomicOr(&c1, 1);
      }
      if(c == 1 && (i & 3) != 0) atomicOr(&c2, 1);
    }
    __syncthreads();
    if(threadIdx.x==0)
      dflag[1] = c0 ? 2 : (c1 ? 3 : (c2 ? 1 : 0));
  }
}

// ---- fused setup: params + cvt action + 3 weight transposes, range-partitioned ----
struct PDesc { const void* src[17]; int cum[18]; };
#define SEG0 1834    // params
#define SEG1 96      // cvt action -> actF (f32)
#define SEG2 1536    // transpose Wg  (2048x3072)
#define SEG3 1280    // transpose W3  (5 x 1024x1024)
#define SEG4 640     // transpose W5  (2560x1024)

__device__ void transpose_dev(const void* src, bf16* dst, int K, int N,
                              int tk, int tn, int head, int dt,
                              unsigned short (*t)[72]){
  size_t hoff = (size_t)head * K * N;
  unsigned short* d = (unsigned short*)dst + hoff;
  int tx = threadIdx.x & 63, ty0 = threadIdx.x >> 6;
  int k0 = tk*64, n0 = tn*64;
  #pragma unroll
  for(int i=0;i<16;i++){
    int ty = ty0*16+i;
    size_t off = hoff + (size_t)(k0+ty)*N + n0+tx;
    unsigned short v;
    if(dt) v = ((const unsigned short*)src)[off];
    else { bf16 b = f2bf(((const float*)src)[off]); v = *(unsigned short*)&b; }
    t[ty][tx] = v;
  }
  __syncthreads();
  #pragma unroll
  for(int i=0;i<16;i++){ int ty = ty0*16+i; d[(size_t)(n0+ty)*K + k0+tx] = t[tx][ty]; }
}

__global__ __launch_bounds__(256) void k_setup(
    PDesc pd, float* paramF, const int* dflag,
    const void* action, float* actF,
    const void* w8, bf16* WgT, const void* w12, bf16* W3T,
    const void* w18, bf16* W5T)
{
  __shared__ unsigned short ts[64][72];
  int bid = blockIdx.x, tid = threadIdx.x;
  int dt = dflag[0];
  if(bid < SEG0){
    int g = bid*256 + tid;
    if(g >= PTOT) return;
    int s = 0;
    while(g >= pd.cum[s+1]) s++;
    int off = g - pd.cum[s];
    paramF[g] = dt ? bf2f(((const bf16*)pd.src[s])[off]) : ((const float*)pd.src[s])[off];
    return;
  }
  bid -= SEG0;
  if(bid < SEG1){
    int i0 = (bid*256 + tid)*4;
    int n = B_*T_*ACT_;
    #pragma unroll
    for(int k=0;k<4;k++){
      int i = i0+k;
      if(i < n) actF[i] = dt ? bf2f(((const bf16*)action)[i]) : ((const float*)action)[i];
    }
    return;
  }
  bid -= SEG1;
  if(bid < SEG2){
    transpose_dev(w8, WgT, GRUK_, GRUN_, bid/48, bid%48, 0, dt, ts);
    return;
  }
  bid -= SEG2;
  if(bid < SEG3){
    int head = bid/256, rem = bid%256;
    transpose_dev(w12, W3T, DETER_, HID_, rem/16, rem%16, head, dt, ts);
    return;
  }
  bid -= SEG3;
  transpose_dev(w18, W5T, OBSK_, HID_, bid/16, bid%16, 0, dt, ts);
}

// ---- MFMA GEMM: 128x32 output tile per block, K split over 4 waves, LDS reduce ----
// mode 0 (grid 512):
//   bid<384:  z2p[part] = A2 @ WgT tile        (96 ct x 4 K-parts, Kc=512)
//   bid>=384: z5p[8+part] = emb[:,t,:] @ W5T[:,1024:] (32 ct x 4 parts, Kc=384)
//             emb read directly from input with dtype dispatch (no embB copy)
// mode 1 (grid 512):
//   bid<256:  z3p[part] = deterB @ W3T[idx]    (32 ct x 8 K-parts, Kc=128)
//   bid>=256: z5p[part] = deterB @ W5T[:,:1024] (32 ct x 8 K-parts, Kc=128)
__global__ __launch_bounds__(256,2) void k_gemm(
    int mode, int t,
    const bf16* A2, const bf16* deterB, const void* embraw,
    const bf16* WgT, const bf16* W3T, const bf16* W5T,
    float* z2p, float* z3p, float* z5p, const int* ens_index, const int* dflag)
{
  __shared__ float red[8192];   // 32 KB
  int bid = blockIdx.x;
  int dtE = dflag[0];
  const bf16 *A0 = nullptr, *BT; float* Cdst;
  int N, ldb, s0 = 0, split = 1<<30, k0, kc;
  int s1 = T_*EMB_, embbase = t*EMB_;
  if(mode == 0){
    if(bid < 384){
      int ct = bid % 96, part = bid / 96;
      N = GRUN_; ldb = GRUK_; BT = WgT + (size_t)ct*32*GRUK_;
      A0 = A2; s0 = GRUK_;
      k0 = part*512; kc = 512;
      Cdst = z2p + (size_t)part*B_*GRUN_ + ct*32;
    } else {
      int b2 = bid - 384;
      int ct = b2 & 31, part = b2 >> 5;
      N = HID_; ldb = OBSK_; BT = W5T + (size_t)ct*32*OBSK_;
      split = DETER_;
      k0 = 1024 + part*384; kc = 384;
      Cdst = z5p + (size_t)(8+part)*B_*HID_ + ct*32;
    }
  } else if(bid < 256){
    int ct = bid & 31, part = bid >> 5;
    int idx = ens_index[t];
    N = HID_; ldb = DETER_; BT = W3T + (size_t)idx*DETER_*HID_ + (size_t)ct*32*DETER_;
    A0 = deterB; s0 = DETER_;
    k0 = part*128; kc = 128;
    Cdst = z3p + (size_t)part*B_*HID_ + ct*32;
  } else {
    int b2 = bid - 256;
    int ct = b2 & 31, part = b2 >> 5;
    N = HID_; ldb = OBSK_; BT = W5T + (size_t)ct*32*OBSK_;
    A0 = deterB; s0 = DETER_;
    k0 = part*128; kc = 128;
    Cdst = z5p + (size_t)part*B_*HID_ + ct*32;
  }
  int tid = threadIdx.x;
  int wave = tid >> 6, lane = tid & 63;
  int quad = lane >> 4, lo = lane & 15;
  int kw0 = k0 + wave*(kc>>2), kw1 = kw0 + (kc>>2);
  f32x4 acc[8][2];
  #pragma unroll
  for(int rf=0;rf<8;rf++){ acc[rf][0]=(f32x4)0.f; acc[rf][1]=(f32x4)0.f; }
  for(int kk=kw0; kk<kw1; kk+=32){
    int kf = kk + quad*8;
    short8 af[8], bfg[2];
    if(kf < split){
      #pragma unroll
      for(int rf=0;rf<8;rf++)
        af[rf] = *(const short8*)(const void*)(A0 + (size_t)(16*rf+lo)*s0 + kf);
    } else {
      int ko = embbase + (kf - split);
      if(dtE){
        const bf16* E = (const bf16*)embraw;
        #pragma unroll
        for(int rf=0;rf<8;rf++)
          af[rf] = *(const short8*)(const void*)(E + (size_t)(16*rf+lo)*s1 + ko);
      } else {
        const float* E = (const float*)embraw;
        #pragma unroll
        for(int rf=0;rf<8;rf++){
          const float* pf = E + (size_t)(16*rf+lo)*s1 + ko;
          f32x4 u0 = *(const f32x4*)pf;
          f32x4 u1 = *(const f32x4*)(pf+4);
          union{ unsigned short s[8]; short8 v; } r;
          #pragma unroll
          for(int w=0;w<4;w++){
            bf16 b0 = f2bf(u0[w]); r.s[w]   = *(unsigned short*)&b0;
            bf16 b1 = f2bf(u1[w]); r.s[4+w] = *(unsigned short*)&b1;
          }
          af[rf] = r.v;
        }
      }
    }
    #pragma unroll
    for(int c=0;c<2;c++)
      bfg[c] = *(const short8*)(const void*)(BT + (size_t)(16*c+lo)*ldb + kf);
    #pragma unroll
    for(int rf=0;rf<8;rf++){
      acc[rf][0] = __builtin_amdgcn_mfma_f32_16x16x32_bf16(af[rf], bfg[0], acc[rf][0], 0,0,0);
      acc[rf][1] = __builtin_amdgcn_mfma_f32_16x16x32_bf16(af[rf], bfg[1], acc[rf][1], 0,0,0);
    }
  }
  // cross-wave reduce: waves 2,3 dump -> waves 0,1 add -> waves 0,1 dump -> all sum pairs
  if(wave >= 2){
    #pragma unroll
    for(int rf=0;rf<8;rf++)
      #pragma unroll
      for(int c=0;c<2;c++)
        *(f32x4*)&red[(((wave-2)*16) + rf*2 + c)*256 + lane*4] = acc[rf][c];
  }
  __syncthreads();
  if(wave < 2){
    #pragma unroll
    for(int rf=0;rf<8;rf++)
      #pragma unroll
      for(int c=0;c<2;c++)
        acc[rf][c] += *(const f32x4*)&red[((wave*16) + rf*2 + c)*256 + lane*4];
  }
  __syncthreads();
  if(wave < 2){
    #pragma unroll
    for(int rf=0;rf<8;rf++)
      #pragma unroll
      for(int c=0;c<2;c++)
        *(f32x4*)&red[((wave*16) + rf*2 + c)*256 + lane*4] = acc[rf][c];
  }
  __syncthreads();
  #pragma unroll
  for(int i=0;i<4;i++){
    int r = (tid>>3) + 32*i;
    int col0 = (tid&7)*4;
    int rf = r>>4, rr = r&15, q = rr>>2, g = rr&3;
    f32x4 v;
    #pragma unroll
    for(int j=0;j<4;j++){
      int col = col0+j; int c = col>>4, lo2 = col&15;
      int lane2 = q*16+lo2;
      v[j] = red[(rf*2 + c)*256 + lane2*4 + g]
           + red[(16 + rf*2 + c)*256 + lane2*4 + g];
    }
    *(f32x4*)(Cdst + (size_t)r*N + col0) = v;
  }
}

// ---- reduce 4 z2 parts + bias, LN over 3072, GRU -> deter (1024 threads) ----
__global__ __launch_bounds__(1024) void k_gru(
    const float* z2p, const float* paramF, const int* dflag,
    const float* determ, float* deter, bf16* deterB, void* out, int t)
{
  __shared__ float sm[32];
  int b = blockIdx.x, tid = threadIdx.x;
  int dt = dflag[0];
  float zz[3]; float s=0.f, s2=0.f;
  #pragma unroll
  for(int i=0;i<3;i++){
    int h = tid + 1024*i;
    float acc = paramF[Pbg + h]
              + z2p[(size_t)b*GRUN_ + h]
              + z2p[(size_t)(B_ + b)*GRUN_ + h]
              + z2p[(size_t)(2*B_ + b)*GRUN_ + h]
              + z2p[(size_t)(3*B_ + b)*GRUN_ + h];
    zz[i]=acc; s+=acc; s2+=acc*acc;
  }
  block_reduce2w(s, s2, sm, 16);
  float mean = s/GRUN_, var = s2/GRUN_ - mean*mean;
  float rstd = rsqrtf(fmaxf(var,0.f) + 1e-5f);
  {
    float lnr = (zz[0] - mean)*rstd*paramF[Pgg+tid     ] + paramF[Pbng+tid     ];
    float lnc = (zz[1] - mean)*rstd*paramF[Pgg+tid+1024] + paramF[Pbng+tid+1024];
    float lnu = (zz[2] - mean)*rstd*paramF[Pgg+tid+2048] + paramF[Pbng+tid+2048];
    float reset = sigm_(lnr);
    float cand  = tanhf(reset*lnc);
    float upd   = sigm_(lnu - 1.f);          // UPDATE_BIAS
    float dn = upd*cand + (1.f-upd)*determ[b*DETER_+tid];
    deter[b*DETER_+tid]  = dn;
    deterB[b*DETER_+tid] = f2bf(dn);
    stout(out, dt, ((size_t)b*T_+t)*OUTW_ + 192 + tid, dn);
  }
}

// ---- tail: heads + outputs + step_in(t+1) (1024 threads) ----
__global__ __launch_bounds__(1024) void k_tail(
    const float* z3p, const float* z5p, const float* paramF, const int* dflag,
    const float* actF, const void* isf,
    const float* deter, float* determ, bf16* A2,
    void* out, const int* ens_index, int t)
{
  __shared__ float hs[1024], xo[1024];
  __shared__ float red[1024];
  __shared__ float dsO[128];
  __shared__ float in44[48];
  __shared__ float sm[32];
  int b = blockIdx.x, tid = threadIdx.x;
  int dt = dflag[0];
  int idx = ens_index[t];
  float a3 = paramF[Pb3 + idx*HID_ + tid];
  #pragma unroll
  for(int p=0;p<8;p++) a3 += z3p[(size_t)(p*B_ + b)*HID_ + tid];
  float a5 = paramF[Pb5 + tid];
  #pragma unroll
  for(int p=0;p<12;p++) a5 += z5p[(size_t)(p*B_ + b)*HID_ + tid];
  float s3=a3, q3=a3*a3, s5=a5, q5=a5*a5;
  block_reduce2w(s3, q3, sm, 16);
  block_reduce2w(s5, q5, sm, 16);
  float m3=s3/HID_, v3=q3/HID_-m3*m3, r3=rsqrtf(fmaxf(v3,0.f)+1e-5f);
  float m5=s5/HID_, v5=q5/HID_-m5*m5, r5=rsqrtf(fmaxf(v5,0.f)+1e-5f);
  hs[tid] = elu_((a3-m3)*r3*paramF[Pg3+idx*HID_+tid] + paramF[Pbn3+idx*HID_+tid]);
  xo[tid] = elu_((a5-m5)*r5*paramF[Pg5+tid] + paramF[Pbn5+tid]);
  __syncthreads();
  int j = tid & 63, cch = tid >> 6;   // 16 chunks of 64
  {
    const float* W = paramF + PW4 + (size_t)idx*HID_*64;
    float a = 0.f;
    for(int k=cch*64; k<cch*64+64; k++) a += hs[k]*W[k*64 + j];
    red[tid] = a;
    __syncthreads();
    if(tid < 64){
      float acc = paramF[Pb4+idx*64+tid];
      for(int c=0;c<16;c++) acc += red[c*64+tid];
      dsO[tid] = acc;
    }
    __syncthreads();
    const float* W6f = paramF + PW6;
    a = 0.f;
    for(int k=cch*64; k<cch*64+64; k++) a += xo[k]*W6f[k*64 + j];
    red[tid] = a;
    __syncthreads();
    if(tid < 64){
      float acc = paramF[Pb6+tid];
      for(int c=0;c<16;c++) acc += red[c*64+tid];
      dsO[64+tid] = acc;
    }
    __syncthreads();
  }
  size_t ob = ((size_t)b*T_ + t)*OUTW_;
  if(tid < 32){
    float pm = dsO[tid];
    float ps = softplus_(dsO[32+tid]) + 0.1f;
    float om = dsO[64+tid];
    float os = softplus_(dsO[96+tid]) + 0.1f;
    stout(out, dt, ob+tid,      om);   // omean
    stout(out, dt, ob+32+tid,   os);   // ostd
    stout(out, dt, ob+64+tid,   om);   // post_stoch
    stout(out, dt, ob+96+tid,   pm);   // pmean
    stout(out, dt, ob+128+tid,  ps);   // pstd
    stout(out, dt, ob+160+tid,  pm);   // prior_stoch
  }
  // ---- step_in for t+1 (block-local stoch carry = dsO[64..95]) ----
  if(t+1 < T_){
    float m = maskv(isf, dflag[1], b*T_ + (t+1));
    if(tid < 32)       in44[tid] = dsO[64+tid]*m;
    else if(tid < 44)  in44[tid] = actF[(size_t)(b*T_+(t+1))*ACT_ + (tid-32)]*m;
    __syncthreads();
    const float* W1f = paramF + PW1;
    float acc = paramF[Pb1 + tid];
    for(int k=0;k<STOCH_+ACT_;k++) acc += in44[k]*W1f[k*HID_ + tid];
    float s = acc, s2 = acc*acc;
    block_reduce2w(s, s2, sm, 16);
    float mean = s/HID_, var = s2/HID_ - mean*mean;
    float rstd = rsqrtf(fmaxf(var,0.f) + 1e-5f);
    float xv = (acc-mean)*rstd*paramF[Pg1+tid] + paramF[Pbn1+tid];
    A2[(size_t)b*GRUK_ + tid] = f2bf(elu_(xv));
    float dm = deter[b*DETER_+tid]*m;
    determ[b*DETER_+tid] = dm;
    A2[(size_t)b*GRUK_ + HID_ + tid] = f2bf(dm);
  }
}

// ---- init: step_in for t=0 with zero carry state (1024 threads) ----
__global__ __launch_bounds__(1024) void k_init(
    const float* actF, const void* isf, const int* dflag,
    const float* paramF, float* determ, bf16* A2)
{
  __shared__ float in44[48];
  __shared__ float sm[32];
  int b = blockIdx.x, tid = threadIdx.x;
  float m = maskv(isf, dflag[1], b*T_);
  if(tid < 32)       in44[tid] = 0.f;
  else if(tid < 44)  in44[tid] = actF[(size_t)(b*T_)*ACT_ + (tid-32)]*m;
  __syncthreads();
  const float* W1f = paramF + PW1;
  float acc = paramF[Pb1 + tid];
  for(int k=0;k<STOCH_+ACT_;k++) acc += in44[k]*W1f[k*HID_ + tid];
  float s = acc, s2 = acc*acc;
  block_reduce2w(s, s2, sm, 16);
  float mean = s/HID_, var = s2/HID_ - mean*mean;
  float rstd = rsqrtf(fmaxf(var,0.f) + 1e-5f);
  float xv = (acc-mean)*rstd*paramF[Pg1+tid] + paramF[Pbn1+tid];
  A2[(size_t)b*GRUK_ + tid] = f2bf(elu_(xv));
  determ[b*DETER_+tid] = 0.f;
  A2[(size_t)b*GRUK_ + HID_ + tid] = f2bf(0.f);
}

extern "C" void kernel_launch(void* const* d_in, const int* in_sizes, int n_in,
                              void* d_out, int out_size, void* d_ws, size_t ws_size,
                              hipStream_t stream)
{
  const void* embed  = d_in[0];
  const void* action = d_in[1];
  const void* isf    = d_in[2];
  const int*  ens_ix = (const int*)d_in[3];

  char* ws = (char*)d_ws;
  float* deter  = (float*)(ws + 0);            // 512 KB
  float* determ = (float*)(ws + 524288);       // 512 KB
  bf16*  A2     = (bf16*) (ws + 1048576);      // 512 KB
  bf16*  deterB = (bf16*) (ws + 1572864);      // 256 KB
  float* z2p    = (float*)(ws + 1835008);      // 6 MB   (4 parts x 128x3072 f32)
  float* z3p    = (float*)(ws + 8126464);      // 4 MB   (8 parts x 128x1024 f32)
  float* z5p    = (float*)(ws + 12320768);     // 6 MB   (12 slots: 8 deter + 4 emb)
  bf16*  WgT    = (bf16*) (ws + 18612224);     // 12.58 MB
  bf16*  W3T    = (bf16*) (ws + 31195136);     // 10.49 MB
  bf16*  W5T    = (bf16*) (ws + 41680896);     // 5.24 MB
  float* paramF = (float*)(ws + 46923776);     // 1.88 MB
  float* actF   = (float*)(ws + 48801280);     // 0.39 MB
  int*   dflag  = (int*)  (ws + 49194496);

  k_detect<<<2,256,0,stream>>>((const unsigned short*)embed, (const unsigned char*)isf, dflag);

  PDesc pd;
  const int srcidx[17] = {4,5,6,7, 9,10,11, 13,14,15, 17, 19,20,21, 23, 16, 22};
  const int sizes[17]  = {45056,1024,1024,1024, 3072,3072,3072, 5120,5120,5120,
                          320, 1024,1024,1024, 64, 327680, 65536};
  int cum = 0;
  for(int i=0;i<17;i++){ pd.src[i] = d_in[srcidx[i]]; pd.cum[i] = cum; cum += sizes[i]; }
  pd.cum[17] = cum;  // 469376

  int setup_grid = SEG0 + SEG1 + SEG2 + SEG3 + SEG4;   // 5386
  k_setup<<<setup_grid,256,0,stream>>>(pd, paramF, dflag, action, actF,
                                       d_in[8], WgT, d_in[12], W3T, d_in[18], W5T);

  k_init<<<B_,1024,0,stream>>>(actF, isf, dflag, paramF, determ, A2);

  for(int t=0; t<T_; t++){
    k_gemm<<<512,256,0,stream>>>(0, t, A2, deterB, embed, WgT, W3T, W5T, z2p, z3p, z5p, ens_ix, dflag);
    k_gru<<<B_,1024,0,stream>>>(z2p, paramF, dflag, determ, deter, deterB, d_out, t);
    k_gemm<<<512,256,0,stream>>>(1, t, A2, deterB, embed, WgT, W3T, W5T, z2p, z3p, z5p, ens_ix, dflag);
    k_tail<<<B_,1024,0,stream>>>(z3p, z5p, paramF, dflag, actF, isf, deter, determ, A2, d_out, ens_ix, t);
  }
}

// Round 8
// 2803.479 us; speedup vs baseline: 1.1998x; 1.1998x over previous
//
#include <hip/hip_runtime.h>
#include <hip/hip_bf16.h>
#include <math.h>

using bf16 = __hip_bfloat16;
using short8 = __attribute__((ext_vector_type(8))) short;
using f32x4  = __attribute__((ext_vector_type(4))) float;

#define B_     128
#define T_     64
#define EMB_   1536
#define ACT_   12
#define STOCH_ 32
#define DETER_ 1024
#define HID_   1024
#define GRUN_  3072
#define GRUK_  2048
#define OBSK_  2560
#define OUTW_  1216   // 6*STOCH + DETER

// canonical f32 param block offsets (floats)
#define PW1   0
#define Pb1   45056
#define Pg1   46080
#define Pbn1  47104
#define Pbg   48128
#define Pgg   51200
#define Pbng  54272
#define Pb3   57344
#define Pg3   62464
#define Pbn3  67584
#define Pb4   72704
#define Pb5   73024
#define Pg5   74048
#define Pbn5  75072
#define Pb6   76096
#define PW4   76160
#define PW6   403840
#define PTOT  469376

__device__ inline float bf2f(bf16 v){ return __bfloat162float(v); }
__device__ inline bf16  f2bf(float v){ return __float2bfloat16(v); }
__device__ inline float elu_(float x){ return x > 0.f ? x : expm1f(x); }
__device__ inline float sigm_(float x){ return 1.f/(1.f+expf(-x)); }
__device__ inline float softplus_(float x){ return fmaxf(x,0.f) + log1pf(expf(-fabsf(x))); }
__device__ inline void stout(void* out, int dt, size_t i, float v){
  if(dt) ((bf16*)out)[i] = f2bf(v); else ((float*)out)[i] = v;
}
__device__ inline float maskv(const void* isf, int enc, int idx){
  float fv;
  if(enc==0)      fv = (float)((const int*)isf)[idx];
  else if(enc==1) fv = (float)((const unsigned char*)isf)[idx];
  else if(enc==2) fv = bf2f(((const bf16*)isf)[idx]);
  else            fv = ((const float*)isf)[idx];
  return (fv != 0.f) ? 0.f : 1.f;
}

// nw-wave block reduction of two values (sum, sumsq); sm needs 2*nw floats
__device__ inline void block_reduce2w(float& a, float& b, float* sm, int nw){
  __syncthreads();
  for(int off=32; off>0; off>>=1){
    a += __shfl_down(a, off);
    b += __shfl_down(b, off);
  }
  int w = threadIdx.x >> 6;
  if((threadIdx.x & 63) == 0){ sm[2*w] = a; sm[2*w+1] = b; }
  __syncthreads();
  float sa = 0.f, sb = 0.f;
  for(int i=0;i<nw;i++){ sa += sm[2*i]; sb += sm[2*i+1]; }
  a = sa; b = sb;
}

// ---- detect: block 0 = float dtype (dflag[0]); block 1 = is_first enc (dflag[1]) ----
__global__ void k_detect(const unsigned short* emb, const unsigned char* isf, int* dflag){
  __shared__ int c0, c1, c2;
  if(threadIdx.x==0){ c0=0; c1=0; c2=0; }
  __syncthreads();
  if(blockIdx.x == 0){
    int c = 0;
    for(int i=threadIdx.x; i<2048; i+=256){
      unsigned short u = emb[2*i];
      int exp8 = (u >> 7) & 0xFF;
      if(exp8 > 140) c++;
    }
    atomicAdd(&c0, c);
    __syncthreads();
    if(threadIdx.x==0) dflag[0] = (c0 < 100) ? 1 : 0;
  } else {
    for(int i=threadIdx.x; i<B_*T_; i+=256){
      unsigned char c = isf[i];
      if(c == 0x3F){
        if((i & 3) == 1) atomicOr(&c0, 1);
        else if((i & 3) == 3) atomicOr(&c1, 1);
      }
      if(c == 1 && (i & 3) != 0) atomicOr(&c2, 1);
    }
    __syncthreads();
    if(threadIdx.x==0)
      dflag[1] = c0 ? 2 : (c1 ? 3 : (c2 ? 1 : 0));
  }
}

// ---- fused setup: params + cvt embed + cvt action + 3 weight transposes ----
struct PDesc { const void* src[17]; int cum[18]; };
#define SEG0 1834    // params
#define SEG1 12288   // cvt embed -> embB (bf16)
#define SEG2 96      // cvt action -> actF (f32)
#define SEG3 1536    // transpose Wg  (2048x3072)
#define SEG4 1280    // transpose W3  (5 x 1024x1024)
#define SEG5 640     // transpose W5  (2560x1024)

__device__ void transpose_dev(const void* src, bf16* dst, int K, int N,
                              int tk, int tn, int head, int dt,
                              unsigned short (*t)[72]){
  size_t hoff = (size_t)head * K * N;
  unsigned short* d = (unsigned short*)dst + hoff;
  int tx = threadIdx.x & 63, ty0 = threadIdx.x >> 6;
  int k0 = tk*64, n0 = tn*64;
  #pragma unroll
  for(int i=0;i<16;i++){
    int ty = ty0*16+i;
    size_t off = hoff + (size_t)(k0+ty)*N + n0+tx;
    unsigned short v;
    if(dt) v = ((const unsigned short*)src)[off];
    else { bf16 b = f2bf(((const float*)src)[off]); v = *(unsigned short*)&b; }
    t[ty][tx] = v;
  }
  __syncthreads();
  #pragma unroll
  for(int i=0;i<16;i++){ int ty = ty0*16+i; d[(size_t)(n0+ty)*K + k0+tx] = t[tx][ty]; }
}

__global__ __launch_bounds__(256) void k_setup(
    PDesc pd, float* paramF, const int* dflag,
    const void* embed, bf16* embB, const void* action, float* actF,
    const void* w8, bf16* WgT, const void* w12, bf16* W3T,
    const void* w18, bf16* W5T)
{
  __shared__ unsigned short ts[64][72];
  int bid = blockIdx.x, tid = threadIdx.x;
  int dt = dflag[0];
  if(bid < SEG0){
    int g = bid*256 + tid;
    if(g >= PTOT) return;
    int s = 0;
    while(g >= pd.cum[s+1]) s++;
    int off = g - pd.cum[s];
    paramF[g] = dt ? bf2f(((const bf16*)pd.src[s])[off]) : ((const float*)pd.src[s])[off];
    return;
  }
  bid -= SEG0;
  if(bid < SEG1){
    int i0 = (bid*256 + tid)*4;
    #pragma unroll
    for(int k=0;k<4;k++){
      int i = i0+k;
      embB[i] = dt ? ((const bf16*)embed)[i] : f2bf(((const float*)embed)[i]);
    }
    return;
  }
  bid -= SEG1;
  if(bid < SEG2){
    int i0 = (bid*256 + tid)*4;
    int n = B_*T_*ACT_;
    #pragma unroll
    for(int k=0;k<4;k++){
      int i = i0+k;
      if(i < n) actF[i] = dt ? bf2f(((const bf16*)action)[i]) : ((const float*)action)[i];
    }
    return;
  }
  bid -= SEG2;
  if(bid < SEG3){
    transpose_dev(w8, WgT, GRUK_, GRUN_, bid/48, bid%48, 0, dt, ts);
    return;
  }
  bid -= SEG3;
  if(bid < SEG4){
    int head = bid/256, rem = bid%256;
    transpose_dev(w12, W3T, DETER_, HID_, rem/16, rem%16, head, dt, ts);
    return;
  }
  bid -= SEG4;
  transpose_dev(w18, W5T, OBSK_, HID_, bid/16, bid%16, 0, dt, ts);
}

// ---- MFMA GEMM: 128x32 output tile per block, K split over 4 waves, LDS reduce ----
// mode 0 (grid 256):
//   bid<192:  z2p[part] = A2 @ WgT tile           (96 ct x 2 parts, Kc=1024)
//   bid>=192: z5p[2+part] = embB[:,t,:] @ W5T[:,1024:] (32 ct x 2 parts, Kc=768)
// mode 1 (grid 256, full device; parts 2,3 alias into z2p which is dead post-gru):
//   bid<128:  z3 = deterB @ W3T[idx]              (32 ct x 4 parts, Kc=256)
//             part<2 -> z3p[part]; part>=2 -> z2p slots 2,3
//   bid>=128: z5d = deterB @ W5T[:,:1024]         (32 ct x 4 parts, Kc=256)
//             part<2 -> z5p[part]; part>=2 -> z2p slots 0,1
__global__ __launch_bounds__(256) void k_gemm(
    int mode, int t,
    const bf16* A2, const bf16* deterB, const bf16* embB,
    const bf16* WgT, const bf16* W3T, const bf16* W5T,
    float* z2p, float* z3p, float* z5p, const int* ens_index)
{
  __shared__ float red[8192];   // 32 KB
  int bid = blockIdx.x;
  const bf16 *A0 = nullptr, *A1 = nullptr, *BT; float* Cdst;
  int N, ldb, s0 = 0, s1 = 0, split = 1<<30, k0, kc;
  if(mode == 0){
    if(bid < 192){
      int ct = bid % 96, part = bid / 96;
      N = GRUN_; ldb = GRUK_; BT = WgT + (size_t)ct*32*GRUK_;
      A0 = A2; s0 = GRUK_;
      k0 = part*1024; kc = 1024;
      Cdst = z2p + (size_t)part*B_*GRUN_ + ct*32;
    } else {
      int b2 = bid - 192;
      int ct = b2 & 31, part = b2 >> 5;
      N = HID_; ldb = OBSK_; BT = W5T + (size_t)ct*32*OBSK_;
      split = DETER_;
      A1 = embB + (size_t)t*EMB_; s1 = T_*EMB_;
      k0 = 1024 + part*768; kc = 768;
      Cdst = z5p + (size_t)(2+part)*B_*HID_ + ct*32;
    }
  } else if(bid < 128){
    int ct = bid & 31, part = bid >> 5;
    int idx = ens_index[t];
    N = HID_; ldb = DETER_; BT = W3T + (size_t)idx*DETER_*HID_ + (size_t)ct*32*DETER_;
    A0 = deterB; s0 = DETER_;
    k0 = part*256; kc = 256;
    // parts 0,1 -> z3p; parts 2,3 -> z2p slots 2,3 (aliased scratch, dead post-gru)
    Cdst = (part < 2 ? z3p + (size_t)part*B_*HID_
                     : z2p + (size_t)part*B_*HID_) + ct*32;
  } else {
    int b2 = bid - 128;
    int ct = b2 & 31, part = b2 >> 5;
    N = HID_; ldb = OBSK_; BT = W5T + (size_t)ct*32*OBSK_;
    A0 = deterB; s0 = DETER_;
    k0 = part*256; kc = 256;
    // parts 0,1 -> z5p; parts 2,3 -> z2p slots 0,1 (aliased scratch)
    Cdst = (part < 2 ? z5p + (size_t)part*B_*HID_
                     : z2p + (size_t)(part-2)*B_*HID_) + ct*32;
  }
  int tid = threadIdx.x;
  int wave = tid >> 6, lane = tid & 63;
  int quad = lane >> 4, lo = lane & 15;
  int kw0 = k0 + wave*(kc>>2), kw1 = kw0 + (kc>>2);
  f32x4 acc[8][2];
  #pragma unroll
  for(int rf=0;rf<8;rf++){ acc[rf][0]=(f32x4)0.f; acc[rf][1]=(f32x4)0.f; }
  for(int kk=kw0; kk<kw1; kk+=32){
    int kf = kk + quad*8;
    const bf16* Ab; int str, ko;
    if(kf < split){ Ab=A0; str=s0; ko=kf; } else { Ab=A1; str=s1; ko=kf-split; }
    short8 af[8], bfg[2];
    #pragma unroll
    for(int rf=0;rf<8;rf++)
      af[rf] = *(const short8*)(const void*)(Ab + (size_t)(16*rf+lo)*str + ko);
    #pragma unroll
    for(int c=0;c<2;c++)
      bfg[c] = *(const short8*)(const void*)(BT + (size_t)(16*c+lo)*ldb + kf);
    #pragma unroll
    for(int rf=0;rf<8;rf++){
      acc[rf][0] = __builtin_amdgcn_mfma_f32_16x16x32_bf16(af[rf], bfg[0], acc[rf][0], 0,0,0);
      acc[rf][1] = __builtin_amdgcn_mfma_f32_16x16x32_bf16(af[rf], bfg[1], acc[rf][1], 0,0,0);
    }
  }
  // cross-wave reduce: waves 2,3 dump -> waves 0,1 add -> waves 0,1 dump -> all sum pairs
  if(wave >= 2){
    #pragma unroll
    for(int rf=0;rf<8;rf++)
      #pragma unroll
      for(int c=0;c<2;c++)
        *(f32x4*)&red[(((wave-2)*16) + rf*2 + c)*256 + lane*4] = acc[rf][c];
  }
  __syncthreads();
  if(wave < 2){
    #pragma unroll
    for(int rf=0;rf<8;rf++)
      #pragma unroll
      for(int c=0;c<2;c++)
        acc[rf][c] += *(const f32x4*)&red[((wave*16) + rf*2 + c)*256 + lane*4];
  }
  __syncthreads();
  if(wave < 2){
    #pragma unroll
    for(int rf=0;rf<8;rf++)
      #pragma unroll
      for(int c=0;c<2;c++)
        *(f32x4*)&red[((wave*16) + rf*2 + c)*256 + lane*4] = acc[rf][c];
  }
  __syncthreads();
  #pragma unroll
  for(int i=0;i<4;i++){
    int r = (tid>>3) + 32*i;
    int col0 = (tid&7)*4;
    int rf = r>>4, rr = r&15, q = rr>>2, g = rr&3;
    f32x4 v;
    #pragma unroll
    for(int j=0;j<4;j++){
      int col = col0+j; int c = col>>4, lo2 = col&15;
      int lane2 = q*16+lo2;
      v[j] = red[(rf*2 + c)*256 + lane2*4 + g]
           + red[(16 + rf*2 + c)*256 + lane2*4 + g];
    }
    *(f32x4*)(Cdst + (size_t)r*N + col0) = v;
  }
}

// ---- reduce 2 z2 parts + bias, LN over 3072, GRU -> deter (1024 threads) ----
__global__ __launch_bounds__(1024) void k_gru(
    const float* z2p, const float* paramF, const int* dflag,
    const float* determ, float* deter, bf16* deterB, void* out, int t)
{
  __shared__ float sm[32];
  int b = blockIdx.x, tid = threadIdx.x;
  int dt = dflag[0];
  float zz[3]; float s=0.f, s2=0.f;
  #pragma unroll
  for(int i=0;i<3;i++){
    int h = tid + 1024*i;
    float acc = paramF[Pbg + h]
              + z2p[(size_t)b*GRUN_ + h]
              + z2p[(size_t)(B_ + b)*GRUN_ + h];
    zz[i]=acc; s+=acc; s2+=acc*acc;
  }
  block_reduce2w(s, s2, sm, 16);
  float mean = s/GRUN_, var = s2/GRUN_ - mean*mean;
  float rstd = rsqrtf(fmaxf(var,0.f) + 1e-5f);
  {
    float lnr = (zz[0] - mean)*rstd*paramF[Pgg+tid     ] + paramF[Pbng+tid     ];
    float lnc = (zz[1] - mean)*rstd*paramF[Pgg+tid+1024] + paramF[Pbng+tid+1024];
    float lnu = (zz[2] - mean)*rstd*paramF[Pgg+tid+2048] + paramF[Pbng+tid+2048];
    float reset = sigm_(lnr);
    float cand  = tanhf(reset*lnc);
    float upd   = sigm_(lnu - 1.f);          // UPDATE_BIAS
    float dn = upd*cand + (1.f-upd)*determ[b*DETER_+tid];
    deter[b*DETER_+tid]  = dn;
    deterB[b*DETER_+tid] = f2bf(dn);
    stout(out, dt, ((size_t)b*T_+t)*OUTW_ + 192 + tid, dn);
  }
}

// ---- tail: heads + outputs + step_in(t+1) (1024 threads) ----
// z3 parts: z3p[0],z3p[1] + z2alias slots 2,3
// z5 parts: z5p[0],z5p[1] (deter) + z2alias slots 0,1 (deter) + z5p[2],z5p[3] (emb)
__global__ __launch_bounds__(1024) void k_tail(
    const float* z3p, const float* z5p, const float* z2alias,
    const float* paramF, const int* dflag,
    const float* actF, const void* isf,
    const float* deter, float* determ, bf16* A2,
    void* out, const int* ens_index, int t)
{
  __shared__ float hs[1024], xo[1024];
  __shared__ float red[1024];
  __shared__ float dsO[128];
  __shared__ float in44[48];
  __shared__ float sm[32];
  int b = blockIdx.x, tid = threadIdx.x;
  int dt = dflag[0];
  int idx = ens_index[t];
  float a3 = paramF[Pb3 + idx*HID_ + tid]
           + z3p[(size_t)b*HID_ + tid] + z3p[(size_t)(B_ + b)*HID_ + tid]
           + z2alias[(size_t)(2*B_ + b)*HID_ + tid] + z2alias[(size_t)(3*B_ + b)*HID_ + tid];
  float a5 = paramF[Pb5 + tid]
           + z5p[(size_t)b*HID_ + tid] + z5p[(size_t)(B_ + b)*HID_ + tid]
           + z2alias[(size_t)b*HID_ + tid] + z2alias[(size_t)(B_ + b)*HID_ + tid]
           + z5p[(size_t)(2*B_ + b)*HID_ + tid] + z5p[(size_t)(3*B_ + b)*HID_ + tid];
  float s3=a3, q3=a3*a3, s5=a5, q5=a5*a5;
  block_reduce2w(s3, q3, sm, 16);
  block_reduce2w(s5, q5, sm, 16);
  float m3=s3/HID_, v3=q3/HID_-m3*m3, r3=rsqrtf(fmaxf(v3,0.f)+1e-5f);
  float m5=s5/HID_, v5=q5/HID_-m5*m5, r5=rsqrtf(fmaxf(v5,0.f)+1e-5f);
  hs[tid] = elu_((a3-m3)*r3*paramF[Pg3+idx*HID_+tid] + paramF[Pbn3+idx*HID_+tid]);
  xo[tid] = elu_((a5-m5)*r5*paramF[Pg5+tid] + paramF[Pbn5+tid]);
  __syncthreads();
  int j = tid & 63, cch = tid >> 6;   // 16 chunks of 64
  {
    const float* W = paramF + PW4 + (size_t)idx*HID_*64;
    float a = 0.f;
    for(int k=cch*64; k<cch*64+64; k++) a += hs[k]*W[k*64 + j];
    red[tid] = a;
    __syncthreads();
    if(tid < 64){
      float acc = paramF[Pb4+idx*64+tid];
      for(int c=0;c<16;c++) acc += red[c*64+tid];
      dsO[tid] = acc;
    }
    __syncthreads();
    const float* W6f = paramF + PW6;
    a = 0.f;
    for(int k=cch*64; k<cch*64+64; k++) a += xo[k]*W6f[k*64 + j];
    red[tid] = a;
    __syncthreads();
    if(tid < 64){
      float acc = paramF[Pb6+tid];
      for(int c=0;c<16;c++) acc += red[c*64+tid];
      dsO[64+tid] = acc;
    }
    __syncthreads();
  }
  size_t ob = ((size_t)b*T_ + t)*OUTW_;
  if(tid < 32){
    float pm = dsO[tid];
    float ps = softplus_(dsO[32+tid]) + 0.1f;
    float om = dsO[64+tid];
    float os = softplus_(dsO[96+tid]) + 0.1f;
    stout(out, dt, ob+tid,      om);   // omean
    stout(out, dt, ob+32+tid,   os);   // ostd
    stout(out, dt, ob+64+tid,   om);   // post_stoch
    stout(out, dt, ob+96+tid,   pm);   // pmean
    stout(out, dt, ob+128+tid,  ps);   // pstd
    stout(out, dt, ob+160+tid,  pm);   // prior_stoch
  }
  // ---- step_in for t+1 (block-local stoch carry = dsO[64..95]) ----
  if(t+1 < T_){
    float m = maskv(isf, dflag[1], b*T_ + (t+1));
    if(tid < 32)       in44[tid] = dsO[64+tid]*m;
    else if(tid < 44)  in44[tid] = actF[(size_t)(b*T_+(t+1))*ACT_ + (tid-32)]*m;
    __syncthreads();
    const float* W1f = paramF + PW1;
    float acc = paramF[Pb1 + tid];
    for(int k=0;k<STOCH_+ACT_;k++) acc += in44[k]*W1f[k*HID_ + tid];
    float s = acc, s2 = acc*acc;
    block_reduce2w(s, s2, sm, 16);
    float mean = s/HID_, var = s2/HID_ - mean*mean;
    float rstd = rsqrtf(fmaxf(var,0.f) + 1e-5f);
    float xv = (acc-mean)*rstd*paramF[Pg1+tid] + paramF[Pbn1+tid];
    A2[(size_t)b*GRUK_ + tid] = f2bf(elu_(xv));
    float dm = deter[b*DETER_+tid]*m;
    determ[b*DETER_+tid] = dm;
    A2[(size_t)b*GRUK_ + HID_ + tid] = f2bf(dm);
  }
}

// ---- init: step_in for t=0 with zero carry state (1024 threads) ----
__global__ __launch_bounds__(1024) void k_init(
    const float* actF, const void* isf, const int* dflag,
    const float* paramF, float* determ, bf16* A2)
{
  __shared__ float in44[48];
  __shared__ float sm[32];
  int b = blockIdx.x, tid = threadIdx.x;
  float m = maskv(isf, dflag[1], b*T_);
  if(tid < 32)       in44[tid] = 0.f;
  else if(tid < 44)  in44[tid] = actF[(size_t)(b*T_)*ACT_ + (tid-32)]*m;
  __syncthreads();
  const float* W1f = paramF + PW1;
  float acc = paramF[Pb1 + tid];
  for(int k=0;k<STOCH_+ACT_;k++) acc += in44[k]*W1f[k*HID_ + tid];
  float s = acc, s2 = acc*acc;
  block_reduce2w(s, s2, sm, 16);
  float mean = s/HID_, var = s2/HID_ - mean*mean;
  float rstd = rsqrtf(fmaxf(var,0.f) + 1e-5f);
  float xv = (acc-mean)*rstd*paramF[Pg1+tid] + paramF[Pbn1+tid];
  A2[(size_t)b*GRUK_ + tid] = f2bf(elu_(xv));
  determ[b*DETER_+tid] = 0.f;
  A2[(size_t)b*GRUK_ + HID_ + tid] = f2bf(0.f);
}

extern "C" void kernel_launch(void* const* d_in, const int* in_sizes, int n_in,
                              void* d_out, int out_size, void* d_ws, size_t ws_size,
                              hipStream_t stream)
{
  const void* embed  = d_in[0];
  const void* action = d_in[1];
  const void* isf    = d_in[2];
  const int*  ens_ix = (const int*)d_in[3];

  char* ws = (char*)d_ws;
  float* deter  = (float*)(ws + 0);            // 512 KB
  float* determ = (float*)(ws + 524288);       // 512 KB
  bf16*  A2     = (bf16*) (ws + 1048576);      // 512 KB
  bf16*  deterB = (bf16*) (ws + 1572864);      // 256 KB
  float* z2p    = (float*)(ws + 1835008);      // 3 MB   (2 z2 parts; slots re-aliased by gemm1)
  float* z3p    = (float*)(ws + 4980736);      // 1 MB   (z3 parts 0,1)
  float* z5p    = (float*)(ws + 6029312);      // 2 MB   (z5d parts 0,1 + z5e parts 0,1)
  bf16*  WgT    = (bf16*) (ws + 8126464);      // 12.58 MB
  bf16*  W3T    = (bf16*) (ws + 20709376);     // 10.49 MB
  bf16*  W5T    = (bf16*) (ws + 31195136);     // 5.24 MB
  float* paramF = (float*)(ws + 36438016);     // 1.88 MB
  bf16*  embB   = (bf16*) (ws + 38315520);     // 25.17 MB
  float* actF   = (float*)(ws + 63481344);     // 0.39 MB
  int*   dflag  = (int*)  (ws + 63874560);

  k_detect<<<2,256,0,stream>>>((const unsigned short*)embed, (const unsigned char*)isf, dflag);

  PDesc pd;
  const int srcidx[17] = {4,5,6,7, 9,10,11, 13,14,15, 17, 19,20,21, 23, 16, 22};
  const int sizes[17]  = {45056,1024,1024,1024, 3072,3072,3072, 5120,5120,5120,
                          320, 1024,1024,1024, 64, 327680, 65536};
  int cum = 0;
  for(int i=0;i<17;i++){ pd.src[i] = d_in[srcidx[i]]; pd.cum[i] = cum; cum += sizes[i]; }
  pd.cum[17] = cum;  // 469376

  int setup_grid = SEG0 + SEG1 + SEG2 + SEG3 + SEG4 + SEG5;   // 17674
  k_setup<<<setup_grid,256,0,stream>>>(pd, paramF, dflag,
                                       embed, embB, action, actF,
                                       d_in[8], WgT, d_in[12], W3T, d_in[18], W5T);

  k_init<<<B_,1024,0,stream>>>(actF, isf, dflag, paramF, determ, A2);

  for(int t=0; t<T_; t++){
    k_gemm<<<256,256,0,stream>>>(0, t, A2, deterB, embB, WgT, W3T, W5T, z2p, z3p, z5p, ens_ix);
    k_gru<<<B_,1024,0,stream>>>(z2p, paramF, dflag, determ, deter, deterB, d_out, t);
    k_gemm<<<256,256,0,stream>>>(1, t, A2, deterB, embB, WgT, W3T, W5T, z2p, z3p, z5p, ens_ix);
    k_tail<<<B_,1024,0,stream>>>(z3p, z5p, z2p, paramF, dflag, actF, isf, deter, determ, A2, d_out, ens_ix, t);
  }
}